// Round 1
// baseline (20.781 us; speedup 1.0000x reference)
//
#include <hip/hip_runtime.h>

// OptimalTrajLoss: B=16384 structures x 64 atoms, 27 periodic images.
// Structure == one 64-lane wave -> segment mean via shfl_xor butterfly.

static constexpr int BSTRUCT = 16384;
static constexpr int ATOMS   = 64;
static constexpr int NATOMS  = BSTRUCT * ATOMS;   // 1048576
static constexpr int BLOCK   = 256;
static constexpr int GRID    = NATOMS / BLOCK;    // 4096

__global__ __launch_bounds__(BLOCK) void otl_main(
    const float* __restrict__ cell,
    const float* __restrict__ x,
    const float* __restrict__ xt,
    const float* __restrict__ xtr,
    float* __restrict__ partial)
{
    const int i    = blockIdx.x * BLOCK + threadIdx.x;  // atom index
    const int s    = i >> 6;                            // structure index
    const int lane = threadIdx.x & 63;
    const int wave = threadIdx.x >> 6;

    // cell[s] row-major 3x3; uniform across the wave (L1 broadcast)
    const float* c = cell + s * 9;
    const float c00 = c[0], c01 = c[1], c02 = c[2];
    const float c10 = c[3], c11 = c[4], c12 = c[5];
    const float c20 = c[6], c21 = c[7], c22 = c[8];

    const float3 xv = reinterpret_cast<const float3*>(x)[i];
    const float3 tv = reinterpret_cast<const float3*>(xt)[i];
    const float3 jv = reinterpret_cast<const float3*>(xtr)[i];

    // d = x_tilde - x ; dist_o = || cell @ (d - off_o) ||
    const float dx = tv.x - xv.x, dy = tv.y - xv.y, dz = tv.z - xv.z;

    // t0 = cell @ d
    const float t0x = c00 * dx + c01 * dy + c02 * dz;
    const float t0y = c10 * dx + c11 * dy + c12 * dz;
    const float t0z = c20 * dx + c21 * dy + c22 * dz;

    // argmin over 27 offsets (o = a*9 + b*3 + g, component = idx-1),
    // staged so column subtractions are shared across the unroll.
    float best = 3.4e38f;
    int   bo   = 0;
    #pragma unroll
    for (int a = 0; a < 3; ++a) {
        const float fa = (float)(a - 1);
        const float ex = t0x - fa * c00;
        const float ey = t0y - fa * c10;
        const float ez = t0z - fa * c20;
        #pragma unroll
        for (int b = 0; b < 3; ++b) {
            const float fb = (float)(b - 1);
            const float fx = ex - fb * c01;
            const float fy = ey - fb * c11;
            const float fz = ez - fb * c21;
            #pragma unroll
            for (int g = 0; g < 3; ++g) {
                const float fg = (float)(g - 1);
                const float gx = fx - fg * c02;
                const float gy = fy - fg * c12;
                const float gz = fz - fg * c22;
                const float d2 = gx * gx + gy * gy + gz * gz;
                const int o = a * 9 + b * 3 + g;
                if (d2 < best) { best = d2; bo = o; }  // strict < == argmin first-min
            }
        }
    }

    // optimal_traj (pre-centering) = d - off[bo]
    const float ox = (float)(bo / 9 - 1);
    const float oy = (float)((bo / 3) % 3 - 1);
    const float oz = (float)(bo % 3 - 1);
    float px = dx - ox, py = dy - oy, pz = dz - oz;

    // per-structure mean via 64-lane butterfly all-reduce
    float sx = px, sy = py, sz = pz;
    #pragma unroll
    for (int m = 32; m > 0; m >>= 1) {
        sx += __shfl_xor(sx, m);
        sy += __shfl_xor(sy, m);
        sz += __shfl_xor(sz, m);
    }
    const float inv = 1.0f / 64.0f;   // num_atoms == 64 exactly
    px -= sx * inv; py -= sy * inv; pz -= sz * inv;

    // l1 contribution
    float l = fabsf(jv.x - px) + fabsf(jv.y - py) + fabsf(jv.z - pz);
    #pragma unroll
    for (int m = 32; m > 0; m >>= 1) l += __shfl_xor(l, m);

    __shared__ float ls[BLOCK / 64];
    if (lane == 0) ls[wave] = l;
    __syncthreads();
    if (threadIdx.x == 0)
        partial[blockIdx.x] = ls[0] + ls[1] + ls[2] + ls[3];
}

__global__ __launch_bounds__(BLOCK) void otl_reduce(
    const float* __restrict__ partial, float* __restrict__ out)
{
    double acc = 0.0;
    for (int i = threadIdx.x; i < GRID; i += BLOCK)
        acc += (double)partial[i];
    #pragma unroll
    for (int m = 32; m > 0; m >>= 1)
        acc += __shfl_xor(acc, m);
    __shared__ double ds[BLOCK / 64];
    const int lane = threadIdx.x & 63, wave = threadIdx.x >> 6;
    if (lane == 0) ds[wave] = acc;
    __syncthreads();
    if (threadIdx.x == 0) {
        const double t = ds[0] + ds[1] + ds[2] + ds[3];
        out[0] = (float)(t / (3.0 * (double)NATOMS));
    }
}

extern "C" void kernel_launch(void* const* d_in, const int* in_sizes, int n_in,
                              void* d_out, int out_size, void* d_ws, size_t ws_size,
                              hipStream_t stream) {
    const float* cell = (const float*)d_in[0];
    const float* x    = (const float*)d_in[1];
    const float* xt   = (const float*)d_in[2];
    const float* xtr  = (const float*)d_in[3];
    // d_in[4] = num_atoms (all 64; batch index = atom>>6, hardcoded)

    float* partial = (float*)d_ws;   // GRID floats = 16 KiB scratch
    float* out     = (float*)d_out;

    otl_main<<<GRID, BLOCK, 0, stream>>>(cell, x, xt, xtr, partial);
    otl_reduce<<<1, BLOCK, 0, stream>>>(partial, out);
}